// Round 6
// baseline (277.796 us; speedup 1.0000x reference)
//
#include <hip/hip_runtime.h>
#include <math.h>

// Problem constants (x: [4, 64, 384, 384] fp32)
#define QLS_T   256             // B*C = 4*64, sequential scan axis
#define QLS_HW  (384 * 384)     // independent spatial locations
#define CHUNK   16              // parallel t-chunks (one per wave)
#define TPC     (QLS_T / CHUNK) // 16 planes per chunk
#define LPB     256             // locations per block (64 lanes x 4 consecutive)

// Quantizer constants from the reference
#define Q_SCALE      16.0f
#define INV_Q_SCALE  (1.0f / 16.0f)
#define QMAXF        7.9375f
#define QMINF        (-8.0f)
#define LUT_IN_SCALE 4096.0f
#define LUT_IN_MAX   32767.0f
#define INV_LUT_OUT  (1.0f / 65536.0f)

// log1p(exp(-d)) = log2(1 + 2^(-d*log2e)) * ln2, on raw v_exp_f32/v_log_f32.
#define NEG_LOG2E_DIV (-1.4426950408889634f / 4096.0f)
#define LN2_X_65536   45426.09375f

// Native clang vector type (HIP float4 is rejected by nontemporal builtin).
typedef float f32x4 __attribute__((ext_vector_type(4)));

__device__ __forceinline__ float qls_step(float s, float v) {
    float diff = fabsf(s - v);
    float d_int = fminf(floorf(diff * LUT_IN_SCALE), LUT_IN_MAX);
    float e  = __builtin_amdgcn_exp2f(d_int * NEG_LOG2E_DIV);
    float lu = rintf(__builtin_amdgcn_logf(1.0f + e) * LN2_X_65536) * INV_LUT_OUT;
    s = fmaxf(s, v) + lu;
    return fminf(fmaxf(s, QMINF), QMAXF);
}

// R8: every global access is a 1KB wave-request (64 lanes x f32x4 contiguous).
// R7 post-mortem: MLP, wave count, chain length, traffic all failed to move
// the ~100us wall; the invariant across all slow variants was 256B
// column-strided requests, while the 6.6TB/s fill uses wide contiguous
// stores. This kernel tests request granularity as the limiter with
// everything else (chunked re-associated scan, single HBM read, LDS merge)
// already validated.
//
// Block: 1024 threads = 16 waves; wave w scans planes [w*16, w*16+16) for
// the block's 256 consecutive locations; partials merged through LDS with
// the same quantized logaddexp op (re-association shift ~1e-5 << 1/32 ->
// absmax stays at the +-1-grid-step 0.0625, as R7 confirmed empirically).
__global__ __launch_bounds__(1024, 4) void qls_f4_kernel(
    const float* __restrict__ x, float* __restrict__ out) {
    const int lane = threadIdx.x & 63;
    const int w    = threadIdx.x >> 6;                 // chunk id, 0..15
    const int loc  = blockIdx.x * LPB + lane * 4;      // 4 consecutive locations
    const size_t base = (size_t)w * TPC * QLS_HW + loc;
    const float* xp = x + base;

    // Chunk scan: 4 independent dependent-chains (one per location), 16
    // f32x4 loads = 1KB wave-requests, compiler pipelines as regs allow;
    // at ~32 waves/CU resident, MLP is ample regardless.
    float s0 = QMINF, s1 = QMINF, s2 = QMINF, s3 = QMINF;
    #pragma unroll
    for (int k = 0; k < TPC; ++k) {
        f32x4 v = *reinterpret_cast<const f32x4*>(xp + (size_t)k * QLS_HW);
        s0 = qls_step(s0, v.x); s1 = qls_step(s1, v.y);
        s2 = qls_step(s2, v.z); s3 = qls_step(s3, v.w);
    }

    // Merge the 16 chunk partials per location through LDS.
    // part[c][loc] layout: writes/reads are lane-stride 16B -> 2-way bank
    // aliasing only (free on CDNA4).
    __shared__ float part[CHUNK][LPB];
    f32x4 sv; sv.x = s0; sv.y = s1; sv.z = s2; sv.w = s3;
    *reinterpret_cast<f32x4*>(&part[w][lane * 4]) = sv;
    __syncthreads();

    f32x4 t4 = *reinterpret_cast<const f32x4*>(&part[0][lane * 4]);
    float t0 = t4.x, t1 = t4.y, t2 = t4.z, t3 = t4.w;
    #pragma unroll
    for (int c = 1; c < CHUNK; ++c) {
        f32x4 p4 = *reinterpret_cast<const f32x4*>(&part[c][lane * 4]);
        t0 = qls_step(t0, p4.x); t1 = qls_step(t1, p4.y);
        t2 = qls_step(t2, p4.z); t3 = qls_step(t3, p4.w);
    }

    // Output: re-read this chunk's planes (L3-absorbed: R1's FETCH_SIZE
    // proved the second x pass costs no HBM), quantize, 1KB NT stores.
    float* op = out + base;
    #pragma unroll
    for (int k = 0; k < TPC; ++k) {
        f32x4 v = *reinterpret_cast<const f32x4*>(xp + (size_t)k * QLS_HW);
        f32x4 q;
        q.x = fminf(fmaxf(rintf((v.x - t0) * Q_SCALE), -128.0f), 127.0f) * INV_Q_SCALE;
        q.y = fminf(fmaxf(rintf((v.y - t1) * Q_SCALE), -128.0f), 127.0f) * INV_Q_SCALE;
        q.z = fminf(fmaxf(rintf((v.z - t2) * Q_SCALE), -128.0f), 127.0f) * INV_Q_SCALE;
        q.w = fminf(fmaxf(rintf((v.w - t3) * Q_SCALE), -128.0f), 127.0f) * INV_Q_SCALE;
        __builtin_nontemporal_store(q, reinterpret_cast<f32x4*>(op + (size_t)k * QLS_HW));
    }
}

extern "C" void kernel_launch(void* const* d_in, const int* in_sizes, int n_in,
                              void* d_out, int out_size, void* d_ws, size_t ws_size,
                              hipStream_t stream) {
    const float* x = (const float*)d_in[0];
    float* out = (float*)d_out;
    const int blocks = QLS_HW / LPB;  // 576 blocks x 1024 threads
    qls_f4_kernel<<<blocks, 1024, 0, stream>>>(x, out);
}